// Round 5
// baseline (265.491 us; speedup 1.0000x reference)
//
#include <hip/hip_runtime.h>
#include <hip/hip_bf16.h>

typedef __attribute__((ext_vector_type(8))) short short8;
typedef __attribute__((ext_vector_type(4))) float f32x4;

#define NB 128
#define NS 4096
#define NH 128
#define NROWS (NB * NS)          // 524288
#define NSTRIP (NROWS / 16)      // 32768 strips of 16 rows
#define GRID1 1024
#define NWAVES (GRID1 * 4)       // 4096 waves
#define ITERS (NSTRIP / NWAVES)  // 8 strips per wave, exact

static __device__ __forceinline__ short8 pack_bf16x8(f32x4 a, f32x4 b) {
    union { __hip_bfloat162 h[4]; short8 s; } u;
    u.h[0] = __float22bfloat162_rn(make_float2(a[0], a[1]));
    u.h[1] = __float22bfloat162_rn(make_float2(a[2], a[3]));
    u.h[2] = __float22bfloat162_rn(make_float2(b[0], b[1]));
    u.h[3] = __float22bfloat162_rn(make_float2(b[2], b[3]));
    return u.s;
}

// tanh(z) = 1 - 2/(1 + exp2(z * 2*log2(e))); saturates correctly at +-inf
static __device__ __forceinline__ float fast_tanh(float z) {
    float e = __builtin_amdgcn_exp2f(z * 2.885390081777927f);
    return 1.0f - 2.0f * __builtin_amdgcn_rcpf(1.0f + e);
}

// Kernel 1: scores[row] = v . tanh(W x_row + b). One wave per 16-row strip.
// W^T packed once per block into LDS as bf16 B-frags (32KB) -> VGPRs freed ->
// 3 blocks/CU (12 waves/CU, 1.5x prior occupancy). x register-pipelined
// distance-2; strip 0/1 loads issued before the W fill so HBM streams from t=0.
__global__ __launch_bounds__(256, 3)
void scores_kernel(const float* __restrict__ x, const float* __restrict__ W,
                   const float* __restrict__ bias_p, const float* __restrict__ v_p,
                   float* __restrict__ scores) {
    __shared__ short8 wfrag[4][8][64];  // [kc][n][lane] = 32 KB
    const int lane = threadIdx.x & 63;
    const int wid  = threadIdx.x >> 6;
    const int col  = lane & 15;  // MFMA col / A row
    const int kg   = lane >> 4;  // k-group 0..3

    const int gw = blockIdx.x * 4 + wid;  // 0..4095
    const float* xp = x + ((long)gw * 16 + col) * NH + kg * 8;
    const long SSTR = (long)NWAVES * 16 * NH;  // float stride between strips

    // x strips 0 and 1 issued FIRST -> HBM streaming starts immediately
    f32x4 xl[8], xl2[8];
#pragma unroll
    for (int kc = 0; kc < 4; ++kc) {
        xl[2 * kc]      = *(const f32x4*)(xp + kc * 32);
        xl[2 * kc + 1]  = *(const f32x4*)(xp + kc * 32 + 4);
        xl2[2 * kc]     = *(const f32x4*)(xp + SSTR + kc * 32);
        xl2[2 * kc + 1] = *(const f32x4*)(xp + SSTR + kc * 32 + 4);
    }

    // cooperative W fill: wave `wid` packs kc=wid for all n; lane packs its own frag
#pragma unroll
    for (int n = 0; n < 8; ++n) {
        const float* wr = W + (n * 16 + col) * NH + wid * 32 + kg * 8;
        f32x4 w0 = *(const f32x4*)(wr);
        f32x4 w1 = *(const f32x4*)(wr + 4);
        wfrag[wid][n][lane] = pack_bf16x8(w0, w1);
    }
    float bias[8], vv[8];
#pragma unroll
    for (int n = 0; n < 8; ++n) {
        bias[n] = bias_p[n * 16 + col];
        vv[n]   = v_p[n * 16 + col];
    }
    __syncthreads();

    auto body = [&](f32x4 (&buf)[8], int it) {
        // convert current strip (compiler waits counted vmcnt; other strip stays in flight)
        short8 a[4];
#pragma unroll
        for (int kc = 0; kc < 4; ++kc) a[kc] = pack_bf16x8(buf[2 * kc], buf[2 * kc + 1]);

        // refill this buffer with strip it+2
        if (it + 2 < ITERS) {
            const float* xn = xp + (long)(it + 2) * SSTR;
#pragma unroll
            for (int kc = 0; kc < 4; ++kc) {
                buf[2 * kc]     = *(const f32x4*)(xn + kc * 32);
                buf[2 * kc + 1] = *(const f32x4*)(xn + kc * 32 + 4);
            }
        }

        // bias folded into acc init; B-frags streamed from LDS
        f32x4 acc[8];
#pragma unroll
        for (int n = 0; n < 8; ++n) acc[n] = (f32x4){bias[n], bias[n], bias[n], bias[n]};
#pragma unroll
        for (int kc = 0; kc < 4; ++kc)
#pragma unroll
            for (int n = 0; n < 8; ++n)
                acc[n] = __builtin_amdgcn_mfma_f32_16x16x32_bf16(a[kc], wfrag[kc][n][lane], acc[n], 0, 0, 0);

        float sj[4] = {0.f, 0.f, 0.f, 0.f};
#pragma unroll
        for (int n = 0; n < 8; ++n)
#pragma unroll
            for (int j = 0; j < 4; ++j)
                sj[j] = fmaf(fast_tanh(acc[n][j]), vv[n], sj[j]);

#pragma unroll
        for (int j = 0; j < 4; ++j) {
            sj[j] += __shfl_xor(sj[j], 1);
            sj[j] += __shfl_xor(sj[j], 2);
            sj[j] += __shfl_xor(sj[j], 4);
            sj[j] += __shfl_xor(sj[j], 8);
        }
        if (col < 4) {
            float o = (col == 0) ? sj[0] : (col == 1) ? sj[1] : (col == 2) ? sj[2] : sj[3];
            scores[((long)gw + (long)it * NWAVES) * 16 + kg * 4 + col] = o;
        }
    };

    for (int it = 0; it < ITERS; it += 2) {
        body(xl, it);
        body(xl2, it + 1);
    }
}

// Kernel 2: single-pass softmax over S=4096 per batch (|score| <= sum|v| < 13
// so exp never overflows -> no max pass needed).
__global__ __launch_bounds__(1024)
void softmax_kernel(float* __restrict__ p) {
    float* row = p + (size_t)blockIdx.x * NS;
    const int t = threadIdx.x;            // 0..1023, 4 elements each
    const int lane = t & 63, wv = t >> 6; // 16 waves
    f32x4 rv = *(const f32x4*)(row + t * 4);
    f32x4 e;
    float s = 0.f;
#pragma unroll
    for (int i = 0; i < 4; ++i) { e[i] = __expf(rv[i]); s += e[i]; }
#pragma unroll
    for (int d = 1; d < 64; d <<= 1) s += __shfl_xor(s, d);
    __shared__ float red[16];
    if (lane == 0) red[wv] = s;
    __syncthreads();
    float tot = 0.f;
#pragma unroll
    for (int i = 0; i < 16; ++i) tot += red[i];
    float inv = 1.0f / tot;
#pragma unroll
    for (int i = 0; i < 4; ++i) e[i] *= inv;
    *(f32x4*)(row + t * 4) = e;
}

extern "C" void kernel_launch(void* const* d_in, const int* in_sizes, int n_in,
                              void* d_out, int out_size, void* d_ws, size_t ws_size,
                              hipStream_t stream) {
    const float* x = (const float*)d_in[0];
    const float* W = (const float*)d_in[1];
    const float* b = (const float*)d_in[2];
    const float* v = (const float*)d_in[3];
    float* out = (float*)d_out;
    // scores staged in d_out, softmax'd in place
    scores_kernel<<<GRID1, 256, 0, stream>>>(x, W, b, v, out);
    softmax_kernel<<<NB, 1024, 0, stream>>>(out);
}

// Round 6
// 176.419 us; speedup vs baseline: 1.5049x; 1.5049x over previous
//
#include <hip/hip_runtime.h>
#include <hip/hip_bf16.h>

typedef __attribute__((ext_vector_type(8))) short short8;
typedef __attribute__((ext_vector_type(4))) float f32x4;

#define NB 128
#define NS 4096
#define NH 128
#define NROWS (NB * NS)          // 524288
#define NSTRIP (NROWS / 16)      // 32768 strips of 16 rows
#define GRID1 1024
#define NWAVES (GRID1 * 4)       // 4096 waves
#define ITERS (NSTRIP / NWAVES)  // 8 strips per wave, exact

static __device__ __forceinline__ short8 pack_bf16x8(f32x4 a, f32x4 b) {
    union { __hip_bfloat162 h[4]; short8 s; } u;
    u.h[0] = __float22bfloat162_rn(make_float2(a[0], a[1]));
    u.h[1] = __float22bfloat162_rn(make_float2(a[2], a[3]));
    u.h[2] = __float22bfloat162_rn(make_float2(b[0], b[1]));
    u.h[3] = __float22bfloat162_rn(make_float2(b[2], b[3]));
    return u.s;
}

// tanh(z) = 1 - 2/(1 + exp2(z * 2*log2(e))); saturates correctly at +-inf
static __device__ __forceinline__ float fast_tanh(float z) {
    float e = __builtin_amdgcn_exp2f(z * 2.885390081777927f);
    return 1.0f - 2.0f * __builtin_amdgcn_rcpf(1.0f + e);
}

// Kernel 1: scores[row] = v . tanh(W x_row + b). One wave per 16-row strip.
// Identical schedule to the 59us register-pipelined variant, with ONE change:
// W^T fragments live in LDS (32KB/block, cooperative fill, lane*16 layout =
// conflict-free) instead of 128 VGPRs -> ~120 VGPR -> 3 blocks/CU (12 waves/CU,
// 1.5x memory parallelism). No lambdas / array refs (R5 scratch-spill lesson).
__global__ __launch_bounds__(256, 3)
void scores_kernel(const float* __restrict__ x, const float* __restrict__ W,
                   const float* __restrict__ bias_p, const float* __restrict__ v_p,
                   float* __restrict__ scores) {
    __shared__ short8 wfrag[4][8][64];  // [kc][n][lane], 32 KB
    const int lane = threadIdx.x & 63;
    const int wid  = threadIdx.x >> 6;
    const int col  = lane & 15;  // MFMA col / A row
    const int kg   = lane >> 4;  // k-group 0..3

    const int gw = blockIdx.x * 4 + wid;          // 0..4095
    const float* xp = x + ((long)gw * 16 + col) * NH + kg * 8;
    const long SSTR = (long)NWAVES * 16 * NH;     // float stride between strips

    // strip-0 x loads issued FIRST so HBM streaming starts immediately
    f32x4 xl[8];
#pragma unroll
    for (int kc = 0; kc < 4; ++kc) {
        xl[2 * kc]     = *(const f32x4*)(xp + kc * 32);
        xl[2 * kc + 1] = *(const f32x4*)(xp + kc * 32 + 4);
    }

    // cooperative W fill (hits L2; overlaps in-flight x loads):
    // wave wid packs kc=wid for all n; each lane packs the frag it will read.
#pragma unroll
    for (int n = 0; n < 8; ++n) {
        const float* wr = W + (n * 16 + col) * NH + wid * 32 + kg * 8;
        f32x4 w0 = *(const f32x4*)(wr);
        f32x4 w1 = *(const f32x4*)(wr + 4);
        wfrag[wid][n][lane] = pack_bf16x8(w0, w1);
    }
    float bias[8], vv[8];
#pragma unroll
    for (int n = 0; n < 8; ++n) {
        bias[n] = bias_p[n * 16 + col];
        vv[n]   = v_p[n * 16 + col];
    }
    __syncthreads();  // once; wfrag is read-only afterwards

    for (int it = 0; it < ITERS; ++it) {
        // convert current strip (counted vmcnt wait; loads issued ~1 iter ago)
        short8 a[4];
#pragma unroll
        for (int kc = 0; kc < 4; ++kc) a[kc] = pack_bf16x8(xl[2 * kc], xl[2 * kc + 1]);

        // issue next strip's loads (xl regs now free)
        if (it + 1 < ITERS) {
            const float* xn = xp + (long)(it + 1) * SSTR;
#pragma unroll
            for (int kc = 0; kc < 4; ++kc) {
                xl[2 * kc]     = *(const f32x4*)(xn + kc * 32);
                xl[2 * kc + 1] = *(const f32x4*)(xn + kc * 32 + 4);
            }
        }

        // bias folded into acc init; B-frags read from LDS each iteration
        f32x4 acc[8];
#pragma unroll
        for (int n = 0; n < 8; ++n) acc[n] = (f32x4){bias[n], bias[n], bias[n], bias[n]};
#pragma unroll
        for (int kc = 0; kc < 4; ++kc)
#pragma unroll
            for (int n = 0; n < 8; ++n)
                acc[n] = __builtin_amdgcn_mfma_f32_16x16x32_bf16(a[kc], wfrag[kc][n][lane], acc[n], 0, 0, 0);

        float sj[4] = {0.f, 0.f, 0.f, 0.f};
#pragma unroll
        for (int n = 0; n < 8; ++n)
#pragma unroll
            for (int j = 0; j < 4; ++j)
                sj[j] = fmaf(fast_tanh(acc[n][j]), vv[n], sj[j]);

        // reduce over the 16 lanes (xor 1/2/4/8 stays within each kg group)
#pragma unroll
        for (int j = 0; j < 4; ++j) {
            sj[j] += __shfl_xor(sj[j], 1);
            sj[j] += __shfl_xor(sj[j], 2);
            sj[j] += __shfl_xor(sj[j], 4);
            sj[j] += __shfl_xor(sj[j], 8);
        }
        if (col < 4) {
            float o = (col == 0) ? sj[0] : (col == 1) ? sj[1] : (col == 2) ? sj[2] : sj[3];
            scores[((long)gw + (long)it * NWAVES) * 16 + kg * 4 + col] = o;
        }
    }
}

// Kernel 2: single-pass softmax over S=4096 per batch (|score| <= sum|v| < 13
// so exp never overflows -> no max pass needed).
__global__ __launch_bounds__(1024)
void softmax_kernel(float* __restrict__ p) {
    float* row = p + (size_t)blockIdx.x * NS;
    const int t = threadIdx.x;            // 0..1023, 4 elements each
    const int lane = t & 63, wv = t >> 6; // 16 waves
    f32x4 rv = *(const f32x4*)(row + t * 4);
    f32x4 e;
    float s = 0.f;
#pragma unroll
    for (int i = 0; i < 4; ++i) { e[i] = __expf(rv[i]); s += e[i]; }
#pragma unroll
    for (int d = 1; d < 64; d <<= 1) s += __shfl_xor(s, d);
    __shared__ float red[16];
    if (lane == 0) red[wv] = s;
    __syncthreads();
    float tot = 0.f;
#pragma unroll
    for (int i = 0; i < 16; ++i) tot += red[i];
    float inv = 1.0f / tot;
#pragma unroll
    for (int i = 0; i < 4; ++i) e[i] *= inv;
    *(f32x4*)(row + t * 4) = e;
}

extern "C" void kernel_launch(void* const* d_in, const int* in_sizes, int n_in,
                              void* d_out, int out_size, void* d_ws, size_t ws_size,
                              hipStream_t stream) {
    const float* x = (const float*)d_in[0];
    const float* W = (const float*)d_in[1];
    const float* b = (const float*)d_in[2];
    const float* v = (const float*)d_in[3];
    float* out = (float*)d_out;
    // scores staged in d_out, softmax'd in place
    scores_kernel<<<GRID1, 256, 0, stream>>>(x, W, b, v, out);
    softmax_kernel<<<NB, 1024, 0, stream>>>(out);
}

// Round 7
// 59.032 us; speedup vs baseline: 4.4974x; 2.9885x over previous
//
#include <hip/hip_runtime.h>
#include <hip/hip_bf16.h>

typedef __attribute__((ext_vector_type(8))) short short8;
typedef __attribute__((ext_vector_type(4))) float f32x4;

#define NB 128
#define NS 4096
#define NH 128
#define NROWS (NB * NS)          // 524288
#define NSTRIP (NROWS / 16)      // 32768 strips of 16 rows
#define GRID1 512
#define NWAVES (GRID1 * 4)       // 2048 waves
#define ITERS (NSTRIP / NWAVES)  // 16 strips per wave, exact

static __device__ __forceinline__ short8 pack_bf16x8(f32x4 a, f32x4 b) {
    union { __hip_bfloat162 h[4]; short8 s; } u;
    u.h[0] = __float22bfloat162_rn(make_float2(a[0], a[1]));
    u.h[1] = __float22bfloat162_rn(make_float2(a[2], a[3]));
    u.h[2] = __float22bfloat162_rn(make_float2(b[0], b[1]));
    u.h[3] = __float22bfloat162_rn(make_float2(b[2], b[3]));
    return u.s;
}

// tanh(z) = 1 - 2/(1 + exp2(z * 2*log2(e))); saturates correctly at +-inf
static __device__ __forceinline__ float fast_tanh(float z) {
    float e = __builtin_amdgcn_exp2f(z * 2.885390081777927f);
    return 1.0f - 2.0f * __builtin_amdgcn_rcpf(1.0f + e);
}

// Kernel 1: scores[row] = v . tanh(W x_row + b). One wave per 16-row strip,
// full W^T in registers as bf16 MFMA B-fragments (proven-good codegen: ~244
// VGPR, no scratch), register-pipelined x loads (issue next strip right after
// converting current). Strip-0 x loads issued BEFORE the W prologue so the
// HBM x-stream starts at cycle 0 and the W/L2 phase hides under it.
__global__ __launch_bounds__(256, 2)
void scores_kernel(const float* __restrict__ x, const float* __restrict__ W,
                   const float* __restrict__ bias_p, const float* __restrict__ v_p,
                   float* __restrict__ scores) {
    const int lane = threadIdx.x & 63;
    const int wid  = threadIdx.x >> 6;
    const int col  = lane & 15;  // MFMA col / A row
    const int kg   = lane >> 4;  // k-group 0..3

    const int gw = blockIdx.x * 4 + wid;          // 0..2047
    const float* xp = x + ((long)gw * 16 + col) * NH + kg * 8;
    const long SSTR = (long)NWAVES * 16 * NH;     // float stride between a wave's strips

    // strip-0 x loads FIRST -> HBM streaming starts immediately
    f32x4 xl[8];
#pragma unroll
    for (int kc = 0; kc < 4; ++kc) {
        xl[2 * kc]     = *(const f32x4*)(xp + kc * 32);
        xl[2 * kc + 1] = *(const f32x4*)(xp + kc * 32 + 4);
    }

    // W prologue (L2-resident after first waves; overlaps in-flight x loads):
    // B[k][n] = W[n][k] (W row-major [o][h])
    short8 bf[4][8];
#pragma unroll
    for (int n = 0; n < 8; ++n) {
        const float* wr = W + (n * 16 + col) * NH;
#pragma unroll
        for (int kc = 0; kc < 4; ++kc) {
            f32x4 w0 = *(const f32x4*)(wr + kc * 32 + kg * 8);
            f32x4 w1 = *(const f32x4*)(wr + kc * 32 + kg * 8 + 4);
            bf[kc][n] = pack_bf16x8(w0, w1);
        }
    }
    float bias[8], vv[8];
#pragma unroll
    for (int n = 0; n < 8; ++n) {
        bias[n] = bias_p[n * 16 + col];
        vv[n]   = v_p[n * 16 + col];
    }

    for (int it = 0; it < ITERS; ++it) {
        // convert current strip (counted vmcnt waits; loads issued ~1 iter ago)
        short8 a[4];
#pragma unroll
        for (int kc = 0; kc < 4; ++kc) a[kc] = pack_bf16x8(xl[2 * kc], xl[2 * kc + 1]);

        // issue next strip's loads (xl regs now free)
        if (it + 1 < ITERS) {
            const float* xn = xp + (long)(it + 1) * SSTR;
#pragma unroll
            for (int kc = 0; kc < 4; ++kc) {
                xl[2 * kc]     = *(const f32x4*)(xn + kc * 32);
                xl[2 * kc + 1] = *(const f32x4*)(xn + kc * 32 + 4);
            }
        }

        // bias folded into acc init: acc[n][j] = preact(row kg*4+j, o = n*16+col)
        f32x4 acc[8];
#pragma unroll
        for (int n = 0; n < 8; ++n) acc[n] = (f32x4){bias[n], bias[n], bias[n], bias[n]};
#pragma unroll
        for (int kc = 0; kc < 4; ++kc)
#pragma unroll
            for (int n = 0; n < 8; ++n)
                acc[n] = __builtin_amdgcn_mfma_f32_16x16x32_bf16(a[kc], bf[kc][n], acc[n], 0, 0, 0);

        float sj[4] = {0.f, 0.f, 0.f, 0.f};
#pragma unroll
        for (int n = 0; n < 8; ++n)
#pragma unroll
            for (int j = 0; j < 4; ++j)
                sj[j] = fmaf(fast_tanh(acc[n][j]), vv[n], sj[j]);

        // reduce over the 16 lanes (xor 1/2/4/8 stays within each kg group)
#pragma unroll
        for (int j = 0; j < 4; ++j) {
            sj[j] += __shfl_xor(sj[j], 1);
            sj[j] += __shfl_xor(sj[j], 2);
            sj[j] += __shfl_xor(sj[j], 4);
            sj[j] += __shfl_xor(sj[j], 8);
        }
        if (col < 4) {
            float o = (col == 0) ? sj[0] : (col == 1) ? sj[1] : (col == 2) ? sj[2] : sj[3];
            scores[((long)gw + (long)it * NWAVES) * 16 + kg * 4 + col] = o;
        }
    }
}

// Kernel 2: single-pass softmax over S=4096 per batch (|score| <= sum|v| < 13
// so exp never overflows -> no max pass needed). Scores are L2-hot from k1.
__global__ __launch_bounds__(1024)
void softmax_kernel(float* __restrict__ p) {
    float* row = p + (size_t)blockIdx.x * NS;
    const int t = threadIdx.x;            // 0..1023, 4 elements each
    const int lane = t & 63, wv = t >> 6; // 16 waves
    f32x4 rv = *(const f32x4*)(row + t * 4);
    f32x4 e;
    float s = 0.f;
#pragma unroll
    for (int i = 0; i < 4; ++i) { e[i] = __expf(rv[i]); s += e[i]; }
#pragma unroll
    for (int d = 1; d < 64; d <<= 1) s += __shfl_xor(s, d);
    __shared__ float red[16];
    if (lane == 0) red[wv] = s;
    __syncthreads();
    float tot = 0.f;
#pragma unroll
    for (int i = 0; i < 16; ++i) tot += red[i];
    float inv = 1.0f / tot;
#pragma unroll
    for (int i = 0; i < 4; ++i) e[i] *= inv;
    *(f32x4*)(row + t * 4) = e;
}

extern "C" void kernel_launch(void* const* d_in, const int* in_sizes, int n_in,
                              void* d_out, int out_size, void* d_ws, size_t ws_size,
                              hipStream_t stream) {
    const float* x = (const float*)d_in[0];
    const float* W = (const float*)d_in[1];
    const float* b = (const float*)d_in[2];
    const float* v = (const float*)d_in[3];
    float* out = (float*)d_out;
    // scores staged in d_out, softmax'd in place
    scores_kernel<<<GRID1, 256, 0, stream>>>(x, W, b, v, out);
    softmax_kernel<<<NB, 1024, 0, stream>>>(out);
}

// Round 9
// 58.858 us; speedup vs baseline: 4.5107x; 1.0030x over previous
//
#include <hip/hip_runtime.h>
#include <hip/hip_bf16.h>

typedef __attribute__((ext_vector_type(8))) short short8;
typedef __attribute__((ext_vector_type(4))) float f32x4;

#define NB 128
#define NS 4096
#define NH 128
#define NROWS (NB * NS)          // 524288
#define NSTRIP (NROWS / 16)      // 32768 strips of 16 rows
#define GRID1 512
#define NWAVES (GRID1 * 4)       // 2048 waves
#define ITERS (NSTRIP / NWAVES)  // 16 strips per wave, exact

static __device__ __forceinline__ short8 pack_bf16x8(f32x4 a, f32x4 b) {
    union { __hip_bfloat162 h[4]; short8 s; } u;
    u.h[0] = __float22bfloat162_rn(make_float2(a[0], a[1]));
    u.h[1] = __float22bfloat162_rn(make_float2(a[2], a[3]));
    u.h[2] = __float22bfloat162_rn(make_float2(b[0], b[1]));
    u.h[3] = __float22bfloat162_rn(make_float2(b[2], b[3]));
    return u.s;
}

// tanh(z) = 1 - 2/(1 + exp2(z * 2*log2(e))); saturates correctly at +-inf
static __device__ __forceinline__ float fast_tanh(float z) {
    float e = __builtin_amdgcn_exp2f(z * 2.885390081777927f);
    return 1.0f - 2.0f * __builtin_amdgcn_rcpf(1.0f + e);
}

// Kernel 1: scores[row] = v . tanh(W x_row + b). One wave per 16-row strip,
// full W^T in registers as bf16 MFMA B-fragments (proven-good codegen, no
// scratch), register-pipelined x loads (issue next strip right after
// converting current). Strip-0 x loads issued BEFORE the W prologue so the
// HBM x-stream starts at cycle 0 and the W/L2 phase hides under it.
// Measured: 59.0 us total, ~5.0 TB/s effective read in k1.
__global__ __launch_bounds__(256, 2)
void scores_kernel(const float* __restrict__ x, const float* __restrict__ W,
                   const float* __restrict__ bias_p, const float* __restrict__ v_p,
                   float* __restrict__ scores) {
    const int lane = threadIdx.x & 63;
    const int wid  = threadIdx.x >> 6;
    const int col  = lane & 15;  // MFMA col / A row
    const int kg   = lane >> 4;  // k-group 0..3

    const int gw = blockIdx.x * 4 + wid;          // 0..2047
    const float* xp = x + ((long)gw * 16 + col) * NH + kg * 8;
    const long SSTR = (long)NWAVES * 16 * NH;     // float stride between a wave's strips

    // strip-0 x loads FIRST -> HBM streaming starts immediately
    f32x4 xl[8];
#pragma unroll
    for (int kc = 0; kc < 4; ++kc) {
        xl[2 * kc]     = *(const f32x4*)(xp + kc * 32);
        xl[2 * kc + 1] = *(const f32x4*)(xp + kc * 32 + 4);
    }

    // W prologue (L2-resident after first waves; overlaps in-flight x loads):
    // B[k][n] = W[n][k] (W row-major [o][h])
    short8 bf[4][8];
#pragma unroll
    for (int n = 0; n < 8; ++n) {
        const float* wr = W + (n * 16 + col) * NH;
#pragma unroll
        for (int kc = 0; kc < 4; ++kc) {
            f32x4 w0 = *(const f32x4*)(wr + kc * 32 + kg * 8);
            f32x4 w1 = *(const f32x4*)(wr + kc * 32 + kg * 8 + 4);
            bf[kc][n] = pack_bf16x8(w0, w1);
        }
    }
    float bias[8], vv[8];
#pragma unroll
    for (int n = 0; n < 8; ++n) {
        bias[n] = bias_p[n * 16 + col];
        vv[n]   = v_p[n * 16 + col];
    }

    for (int it = 0; it < ITERS; ++it) {
        // convert current strip (counted vmcnt waits; loads issued ~1 iter ago)
        short8 a[4];
#pragma unroll
        for (int kc = 0; kc < 4; ++kc) a[kc] = pack_bf16x8(xl[2 * kc], xl[2 * kc + 1]);

        // issue next strip's loads (xl regs now free)
        if (it + 1 < ITERS) {
            const float* xn = xp + (long)(it + 1) * SSTR;
#pragma unroll
            for (int kc = 0; kc < 4; ++kc) {
                xl[2 * kc]     = *(const f32x4*)(xn + kc * 32);
                xl[2 * kc + 1] = *(const f32x4*)(xn + kc * 32 + 4);
            }
        }

        // bias folded into acc init: acc[n][j] = preact(row kg*4+j, o = n*16+col)
        f32x4 acc[8];
#pragma unroll
        for (int n = 0; n < 8; ++n) acc[n] = (f32x4){bias[n], bias[n], bias[n], bias[n]};
#pragma unroll
        for (int kc = 0; kc < 4; ++kc)
#pragma unroll
            for (int n = 0; n < 8; ++n)
                acc[n] = __builtin_amdgcn_mfma_f32_16x16x32_bf16(a[kc], bf[kc][n], acc[n], 0, 0, 0);

        float sj[4] = {0.f, 0.f, 0.f, 0.f};
#pragma unroll
        for (int n = 0; n < 8; ++n)
#pragma unroll
            for (int j = 0; j < 4; ++j)
                sj[j] = fmaf(fast_tanh(acc[n][j]), vv[n], sj[j]);

        // reduce over the 16 lanes (xor 1/2/4/8 stays within each kg group)
#pragma unroll
        for (int j = 0; j < 4; ++j) {
            sj[j] += __shfl_xor(sj[j], 1);
            sj[j] += __shfl_xor(sj[j], 2);
            sj[j] += __shfl_xor(sj[j], 4);
            sj[j] += __shfl_xor(sj[j], 8);
        }
        if (col < 4) {
            float o = (col == 0) ? sj[0] : (col == 1) ? sj[1] : (col == 2) ? sj[2] : sj[3];
            scores[((long)gw + (long)it * NWAVES) * 16 + kg * 4 + col] = o;
        }
    }
}

// Kernel 2: single-pass softmax over S=4096 per batch (|score| <= sum|v| < 13
// so exp never overflows -> no max pass needed). Scores are L2-hot from k1.
__global__ __launch_bounds__(1024)
void softmax_kernel(float* __restrict__ p) {
    float* row = p + (size_t)blockIdx.x * NS;
    const int t = threadIdx.x;            // 0..1023, 4 elements each
    const int lane = t & 63, wv = t >> 6; // 16 waves
    f32x4 rv = *(const f32x4*)(row + t * 4);
    f32x4 e;
    float s = 0.f;
#pragma unroll
    for (int i = 0; i < 4; ++i) { e[i] = __expf(rv[i]); s += e[i]; }
#pragma unroll
    for (int d = 1; d < 64; d <<= 1) s += __shfl_xor(s, d);
    __shared__ float red[16];
    if (lane == 0) red[wv] = s;
    __syncthreads();
    float tot = 0.f;
#pragma unroll
    for (int i = 0; i < 16; ++i) tot += red[i];
    float inv = 1.0f / tot;
#pragma unroll
    for (int i = 0; i < 4; ++i) e[i] *= inv;
    *(f32x4*)(row + t * 4) = e;
}

extern "C" void kernel_launch(void* const* d_in, const int* in_sizes, int n_in,
                              void* d_out, int out_size, void* d_ws, size_t ws_size,
                              hipStream_t stream) {
    const float* x = (const float*)d_in[0];
    const float* W = (const float*)d_in[1];
    const float* b = (const float*)d_in[2];
    const float* v = (const float*)d_in[3];
    float* out = (float*)d_out;
    // scores staged in d_out, softmax'd in place
    scores_kernel<<<GRID1, 256, 0, stream>>>(x, W, b, v, out);
    softmax_kernel<<<NB, 1024, 0, stream>>>(out);
}